// Round 1
// baseline (578.404 us; speedup 1.0000x reference)
//
#include <hip/hip_runtime.h>

typedef _Float16 half8 __attribute__((ext_vector_type(8)));
typedef _Float16 half4 __attribute__((ext_vector_type(4)));
typedef float f32x4 __attribute__((ext_vector_type(4)));

#define ROWF 256   // floats per token row (H*d = 4*64)
#define HDIM 64

// intra-tile token offset: j = tt*64 + th*8 + tw  ->  2304*tt + 48*th + tw
__device__ __forceinline__ int intra_off(int j) {
    return 2304 * (j >> 6) + 48 * ((j >> 3) & 7) + (j & 7);
}

__global__ __launch_bounds__(256) void sta_kernel(
    const float* __restrict__ qg, const float* __restrict__ kg,
    const float* __restrict__ vg, float* __restrict__ out)
{
    // LDS: K chunk [64 keys][72 d], V chunk transposed [64 d][72 keys], P per-wave [16 q][72 k]
    __shared__ _Float16 Klds[64 * 72];
    __shared__ _Float16 Vlds[64 * 72];
    __shared__ _Float16 Plds[4 * 16 * 72];

    const int tid  = threadIdx.x;
    const int wave = tid >> 6;
    const int lane = tid & 63;
    const int g    = lane >> 4;   // 0..3
    const int c    = lane & 15;   // 0..15

    const int bid  = blockIdx.x;
    const int tile = bid >> 3;          // 0..215
    const int head = (bid >> 1) & 3;    // 0..3
    const int rb   = bid & 1;           // query half: rows [rb*192, rb*192+192)

    const int nt = tile / 36;
    const int nh = (tile / 6) % 6;
    const int nw = tile % 6;
    const int tbase = 13824 * nt + 384 * nh + 8 * nw;

    // --- key-tile gather list per head window ---
    int ktl[4]; int W;
    const int t0 = nt < 4 ? nt : 4;
    const int h0 = nh < 4 ? nh : 4;
    const int w0 = nw < 4 ? nw : 4;
    if (head == 0) {        // (2,1,1)
        W = 2; ktl[0] = (t0 * 6 + nh) * 6 + nw; ktl[1] = ((t0 + 1) * 6 + nh) * 6 + nw;
    } else if (head == 1) { // (1,2,2)
        W = 4;
        ktl[0] = (nt * 6 + h0) * 6 + w0;       ktl[1] = ktl[0] + 1;
        ktl[2] = (nt * 6 + h0 + 1) * 6 + w0;   ktl[3] = ktl[2] + 1;
    } else if (head == 2) { // (1,1,2)
        W = 2; ktl[0] = (nt * 6 + nh) * 6 + w0; ktl[1] = ktl[0] + 1;
    } else {                // (1,1,1)
        W = 1; ktl[0] = tile;
    }

    // --- load Q fragments, scale folded: 1/sqrt(64) * log2(e) (exp2 domain) ---
    const float qscale = 0.125f * 1.44269504f;
    half8 qf[3][2];
    #pragma unroll
    for (int mt = 0; mt < 3; ++mt) {
        const int j = rb * 192 + wave * 48 + mt * 16 + c;   // A-frag row = lane&15
        const float* qp = qg + (size_t)(tbase + intra_off(j)) * ROWF + head * HDIM;
        #pragma unroll
        for (int kc = 0; kc < 2; ++kc) {
            f32x4 a = *(const f32x4*)(qp + kc * 32 + g * 8);
            f32x4 b = *(const f32x4*)(qp + kc * 32 + g * 8 + 4);
            half8 f;
            #pragma unroll
            for (int e = 0; e < 4; ++e) {
                f[e]     = (_Float16)(a[e] * qscale);
                f[e + 4] = (_Float16)(b[e] * qscale);
            }
            qf[mt][kc] = f;
        }
    }

    f32x4 oacc[3][4];
    float m_r[3][4], l_r[3][4];
    #pragma unroll
    for (int mt = 0; mt < 3; ++mt) {
        #pragma unroll
        for (int dt = 0; dt < 4; ++dt) oacc[mt][dt] = (f32x4){0.f, 0.f, 0.f, 0.f};
        #pragma unroll
        for (int r = 0; r < 4; ++r) { m_r[mt][r] = -1e30f; l_r[mt][r] = 0.f; }
    }

    const int sr = tid >> 4;         // staging row group 0..15
    const int sc = (tid & 15) * 4;   // staging d offset

    for (int wi = 0; wi < W; ++wi) {
        const int kt  = ktl[wi];
        const int kb  = 13824 * (kt / 36) + 384 * ((kt / 6) % 6) + 8 * (kt % 6);
        for (int ktt = 0; ktt < 6; ++ktt) {
            __syncthreads();   // previous chunk's LDS reads complete
            // --- stage 64 keys: K -> [key][d] f16, V -> [d][key] f16 ---
            #pragma unroll
            for (int i = 0; i < 4; ++i) {
                const int r = i * 16 + sr;
                const int s = kb + 2304 * ktt + 48 * (r >> 3) + (r & 7);
                f32x4 kv = *(const f32x4*)(kg + (size_t)s * ROWF + head * HDIM + sc);
                f32x4 vv = *(const f32x4*)(vg + (size_t)s * ROWF + head * HDIM + sc);
                half4 kh;
                #pragma unroll
                for (int e = 0; e < 4; ++e) kh[e] = (_Float16)kv[e];
                *(half4*)&Klds[r * 72 + sc] = kh;
                Vlds[(sc + 0) * 72 + r] = (_Float16)vv[0];
                Vlds[(sc + 1) * 72 + r] = (_Float16)vv[1];
                Vlds[(sc + 2) * 72 + r] = (_Float16)vv[2];
                Vlds[(sc + 3) * 72 + r] = (_Float16)vv[3];
            }
            __syncthreads();

            #pragma unroll
            for (int mt = 0; mt < 3; ++mt) {
                // --- S = Q K^T (exp2-scaled domain) ---
                f32x4 sacc[4];
                #pragma unroll
                for (int jt = 0; jt < 4; ++jt) sacc[jt] = (f32x4){0.f, 0.f, 0.f, 0.f};
                #pragma unroll
                for (int kc = 0; kc < 2; ++kc) {
                    const half8 a = qf[mt][kc];
                    #pragma unroll
                    for (int jt = 0; jt < 4; ++jt) {
                        const half8 b = *(const half8*)&Klds[(jt * 16 + c) * 72 + kc * 32 + g * 8];
                        sacc[jt] = __builtin_amdgcn_mfma_f32_16x16x32_f16(a, b, sacc[jt], 0, 0, 0);
                    }
                }
                // --- online softmax; lane holds rows g*4+r, key jt*16+c ---
                float alpha[4], rsum[4];
                #pragma unroll
                for (int r = 0; r < 4; ++r) {
                    float mm = fmaxf(fmaxf(sacc[0][r], sacc[1][r]),
                                     fmaxf(sacc[2][r], sacc[3][r]));
                    #pragma unroll
                    for (int mk = 1; mk <= 8; mk <<= 1)
                        mm = fmaxf(mm, __shfl_xor(mm, mk, 64));
                    const float mn = fmaxf(m_r[mt][r], mm);
                    alpha[r] = exp2f(m_r[mt][r] - mn);
                    m_r[mt][r] = mn;
                    rsum[r] = 0.f;
                }
                #pragma unroll
                for (int jt = 0; jt < 4; ++jt) {
                    #pragma unroll
                    for (int r = 0; r < 4; ++r) {
                        const float p = exp2f(sacc[jt][r] - m_r[mt][r]);
                        rsum[r] += p;
                        Plds[wave * 1152 + (g * 4 + r) * 72 + jt * 16 + c] = (_Float16)p;
                    }
                }
                #pragma unroll
                for (int r = 0; r < 4; ++r) {
                    #pragma unroll
                    for (int mk = 1; mk <= 8; mk <<= 1)
                        rsum[r] += __shfl_xor(rsum[r], mk, 64);
                    l_r[mt][r] = l_r[mt][r] * alpha[r] + rsum[r];
                }
                #pragma unroll
                for (int dt = 0; dt < 4; ++dt)
                    #pragma unroll
                    for (int r = 0; r < 4; ++r)
                        oacc[mt][dt][r] *= alpha[r];
                // --- O += P V ---
                #pragma unroll
                for (int kc = 0; kc < 2; ++kc) {
                    const half8 pa = *(const half8*)&Plds[wave * 1152 + c * 72 + kc * 32 + g * 8];
                    #pragma unroll
                    for (int dt = 0; dt < 4; ++dt) {
                        const half8 vb = *(const half8*)&Vlds[(dt * 16 + c) * 72 + kc * 32 + g * 8];
                        oacc[mt][dt] = __builtin_amdgcn_mfma_f32_16x16x32_f16(pa, vb, oacc[mt][dt], 0, 0, 0);
                    }
                }
            }
        }
    }

    // --- epilogue: normalize and scatter back through untile mapping ---
    #pragma unroll
    for (int mt = 0; mt < 3; ++mt) {
        #pragma unroll
        for (int r = 0; r < 4; ++r) {
            const int j = rb * 192 + wave * 48 + mt * 16 + g * 4 + r;  // D row = (lane>>4)*4+r
            float* op = out + (size_t)(tbase + intra_off(j)) * ROWF + head * HDIM;
            const float linv = 1.0f / l_r[mt][r];
            #pragma unroll
            for (int dt = 0; dt < 4; ++dt)
                op[dt * 16 + c] = oacc[mt][dt][r] * linv;
        }
    }
}

extern "C" void kernel_launch(void* const* d_in, const int* in_sizes, int n_in,
                              void* d_out, int out_size, void* d_ws, size_t ws_size,
                              hipStream_t stream) {
    const float* q = (const float*)d_in[0];
    const float* k = (const float*)d_in[1];
    const float* v = (const float*)d_in[2];
    float* o = (float*)d_out;
    dim3 grid(216 * 4 * 2);   // tile * head * query-half
    dim3 block(256);
    hipLaunchKernelGGL(sta_kernel, grid, block, 0, stream, q, k, v, o);
}

// Round 2
// 559.340 us; speedup vs baseline: 1.0341x; 1.0341x over previous
//
#include <hip/hip_runtime.h>

typedef _Float16 half8 __attribute__((ext_vector_type(8)));
typedef _Float16 half4 __attribute__((ext_vector_type(4)));
typedef float f32x4 __attribute__((ext_vector_type(4)));

#define ROWF 256   // floats per token row (H*d = 4*64)
#define HDIM 64
#define KST 72     // LDS stride in halves (144B, keeps b128 reads 16B-aligned)
#define PST (16 * KST)

// intra-tile token offset: j = tt*64 + th*8 + tw  ->  2304*tt + 48*th + tw
__device__ __forceinline__ int intra_off(int j) {
    return 2304 * (j >> 6) + 48 * ((j >> 3) & 7) + (j & 7);
}

__global__ __launch_bounds__(256) void sta_kernel(
    const float* __restrict__ qg, const float* __restrict__ kg,
    const float* __restrict__ vg, float* __restrict__ out)
{
    __shared__ _Float16 Klds[64 * KST];   // [key][d]
    __shared__ _Float16 Vlds[64 * KST];   // transposed: [d][key]
    __shared__ _Float16 Plds[4 * PST];    // per-wave [q=16][key=64]

    const int tid  = threadIdx.x;
    const int wave = tid >> 6;
    const int lane = tid & 63;
    const int g    = lane >> 4;   // 0..3
    const int c    = lane & 15;   // 0..15

    const int bid  = blockIdx.x;
    const int tile = bid >> 3;          // 0..215
    const int head = (bid >> 1) & 3;    // 0..3
    const int rb   = bid & 1;           // query half

    const int nt = tile / 36;
    const int nh = (tile / 6) % 6;
    const int nw = tile % 6;
    const int tbase = 13824 * nt + 384 * nh + 8 * nw;

    // --- key-tile gather list per head window ---
    int ktl[4]; int W;
    const int t0 = nt < 4 ? nt : 4;
    const int h0 = nh < 4 ? nh : 4;
    const int w0 = nw < 4 ? nw : 4;
    if (head == 0) {        // (2,1,1)
        W = 2; ktl[0] = (t0 * 6 + nh) * 6 + nw; ktl[1] = ((t0 + 1) * 6 + nh) * 6 + nw;
    } else if (head == 1) { // (1,2,2)
        W = 4;
        ktl[0] = (nt * 6 + h0) * 6 + w0;       ktl[1] = ktl[0] + 1;
        ktl[2] = (nt * 6 + h0 + 1) * 6 + w0;   ktl[3] = ktl[2] + 1;
    } else if (head == 2) { // (1,1,2)
        W = 2; ktl[0] = (nt * 6 + nh) * 6 + w0; ktl[1] = ktl[0] + 1;
    } else {                // (1,1,1)
        W = 1; ktl[0] = tile;
    }

    // --- Q fragments (B operand now; same register layout): lane holds Q[q=mt*16+c][d-slice]
    const float qscale = 0.125f * 1.44269504f;   // 1/sqrt(64) * log2(e)
    half8 qf[3][2];
    #pragma unroll
    for (int mt = 0; mt < 3; ++mt) {
        const int j = rb * 192 + wave * 48 + mt * 16 + c;
        const float* qp = qg + (size_t)(tbase + intra_off(j)) * ROWF + head * HDIM;
        #pragma unroll
        for (int kc = 0; kc < 2; ++kc) {
            f32x4 a = *(const f32x4*)(qp + kc * 32 + g * 8);
            f32x4 b = *(const f32x4*)(qp + kc * 32 + g * 8 + 4);
            half8 f;
            #pragma unroll
            for (int e = 0; e < 4; ++e) {
                f[e]     = (_Float16)(a[e] * qscale);
                f[e + 4] = (_Float16)(b[e] * qscale);
            }
            qf[mt][kc] = f;
        }
    }

    f32x4 oacc[3][4];
    float m_r[3], l_r[3];   // per-lane state for q = mt*16 + c  (one scalar per mt now)
    #pragma unroll
    for (int mt = 0; mt < 3; ++mt) {
        #pragma unroll
        for (int dt = 0; dt < 4; ++dt) oacc[mt][dt] = (f32x4){0.f, 0.f, 0.f, 0.f};
        m_r[mt] = -1e30f; l_r[mt] = 0.f;
    }

    const int r4  = tid >> 4;   // key group of 4 (0..15)
    const int sc4 = tid & 15;   // d group of 4 (0..15)

    for (int wi = 0; wi < W; ++wi) {
        const int kt = ktl[wi];
        const int kb = 13824 * (kt / 36) + 384 * ((kt / 6) % 6) + 8 * (kt % 6);
        for (int ktt = 0; ktt < 6; ++ktt) {
            __syncthreads();   // previous chunk's LDS reads complete
            // --- stage 64 keys; each thread owns a 4-key x 4-d block ---
            half4 vt[4];   // vt[e][j] = V[key 4*r4+j][d 4*sc4+e]  (in-register transpose)
            #pragma unroll
            for (int j = 0; j < 4; ++j) {
                const int r = r4 * 4 + j;
                const int s = kb + 2304 * ktt + 48 * (r >> 3) + (r & 7);
                const float* kp = kg + (size_t)s * ROWF + head * HDIM + sc4 * 4;
                const float* vp = vg + (size_t)s * ROWF + head * HDIM + sc4 * 4;
                const f32x4 kv = *(const f32x4*)kp;
                const f32x4 vv = *(const f32x4*)vp;
                half4 kh;
                #pragma unroll
                for (int e = 0; e < 4; ++e) kh[e] = (_Float16)kv[e];
                *(half4*)&Klds[r * KST + sc4 * 4] = kh;
                #pragma unroll
                for (int e = 0; e < 4; ++e) vt[e][j] = (_Float16)vv[e];
            }
            #pragma unroll
            for (int e = 0; e < 4; ++e)
                *(half4*)&Vlds[(sc4 * 4 + e) * KST + r4 * 4] = vt[e];
            __syncthreads();

            #pragma unroll
            for (int mt = 0; mt < 3; ++mt) {
                // --- S^T = K * Q^T : lane (g,c) holds S[q=c][key = jt*16 + g*4 + r] ---
                f32x4 sacc[4];
                #pragma unroll
                for (int jt = 0; jt < 4; ++jt) sacc[jt] = (f32x4){0.f, 0.f, 0.f, 0.f};
                #pragma unroll
                for (int kc = 0; kc < 2; ++kc) {
                    const half8 qfr = qf[mt][kc];
                    #pragma unroll
                    for (int jt = 0; jt < 4; ++jt) {
                        const half8 kf = *(const half8*)&Klds[(jt * 16 + c) * KST + kc * 32 + g * 8];
                        sacc[jt] = __builtin_amdgcn_mfma_f32_16x16x32_f16(kf, qfr, sacc[jt], 0, 0, 0);
                    }
                }
                // --- online softmax over 64 keys; 16 in-lane + 2 shuffles ---
                float mj[4];
                #pragma unroll
                for (int jt = 0; jt < 4; ++jt)
                    mj[jt] = fmaxf(fmaxf(sacc[jt][0], sacc[jt][1]),
                                   fmaxf(sacc[jt][2], sacc[jt][3]));
                float mm = fmaxf(fmaxf(mj[0], mj[1]), fmaxf(mj[2], mj[3]));
                mm = fmaxf(mm, __shfl_xor(mm, 16, 64));
                mm = fmaxf(mm, __shfl_xor(mm, 32, 64));
                const float mn = fmaxf(m_r[mt], mm);
                const float alpha = exp2f(m_r[mt] - mn);
                m_r[mt] = mn;

                float rsj[4];
                #pragma unroll
                for (int jt = 0; jt < 4; ++jt) {
                    const float p0 = exp2f(sacc[jt][0] - mn);
                    const float p1 = exp2f(sacc[jt][1] - mn);
                    const float p2 = exp2f(sacc[jt][2] - mn);
                    const float p3 = exp2f(sacc[jt][3] - mn);
                    rsj[jt] = (p0 + p1) + (p2 + p3);
                    half4 ph;
                    ph[0] = (_Float16)p0; ph[1] = (_Float16)p1;
                    ph[2] = (_Float16)p2; ph[3] = (_Float16)p3;
                    // P[q=c][keys jt*16+g*4 .. +3] -- one 8B write per jt
                    *(half4*)&Plds[wave * PST + c * KST + jt * 16 + g * 4] = ph;
                }
                float rs = (rsj[0] + rsj[1]) + (rsj[2] + rsj[3]);
                rs += __shfl_xor(rs, 16, 64);
                rs += __shfl_xor(rs, 32, 64);
                l_r[mt] = l_r[mt] * alpha + rs;

                // broadcast alpha for this lane's oacc rows (q = g*4+r)
                float ar[4];
                #pragma unroll
                for (int r = 0; r < 4; ++r) ar[r] = __shfl(alpha, g * 4 + r, 16);
                #pragma unroll
                for (int dt = 0; dt < 4; ++dt)
                    #pragma unroll
                    for (int r = 0; r < 4; ++r)
                        oacc[mt][dt][r] *= ar[r];

                // --- O += P V : A = P[q][k], B = V^T[d][k] ---
                #pragma unroll
                for (int kc = 0; kc < 2; ++kc) {
                    const half8 pa = *(const half8*)&Plds[wave * PST + c * KST + kc * 32 + g * 8];
                    #pragma unroll
                    for (int dt = 0; dt < 4; ++dt) {
                        const half8 vb = *(const half8*)&Vlds[(dt * 16 + c) * KST + kc * 32 + g * 8];
                        oacc[mt][dt] = __builtin_amdgcn_mfma_f32_16x16x32_f16(pa, vb, oacc[mt][dt], 0, 0, 0);
                    }
                }
            }
        }
    }

    // --- epilogue: normalize (1/l broadcast per row) and scatter via untile ---
    #pragma unroll
    for (int mt = 0; mt < 3; ++mt) {
        float lq[4];
        #pragma unroll
        for (int r = 0; r < 4; ++r) lq[r] = __shfl(l_r[mt], g * 4 + r, 16);
        #pragma unroll
        for (int r = 0; r < 4; ++r) {
            const int j = rb * 192 + wave * 48 + mt * 16 + g * 4 + r;
            float* op = out + (size_t)(tbase + intra_off(j)) * ROWF + head * HDIM;
            const float linv = 1.0f / lq[r];
            #pragma unroll
            for (int dt = 0; dt < 4; ++dt)
                op[dt * 16 + c] = oacc[mt][dt][r] * linv;
        }
    }
}

extern "C" void kernel_launch(void* const* d_in, const int* in_sizes, int n_in,
                              void* d_out, int out_size, void* d_ws, size_t ws_size,
                              hipStream_t stream) {
    const float* q = (const float*)d_in[0];
    const float* k = (const float*)d_in[1];
    const float* v = (const float*)d_in[2];
    float* o = (float*)d_out;
    dim3 grid(216 * 4 * 2);   // tile * head * query-half
    dim3 block(256);
    hipLaunchKernelGGL(sta_kernel, grid, block, 0, stream, q, k, v, o);
}

// Round 5
// 385.640 us; speedup vs baseline: 1.4999x; 1.4504x over previous
//
#include <hip/hip_runtime.h>

typedef _Float16 half4 __attribute__((ext_vector_type(4)));
typedef _Float16 half8 __attribute__((ext_vector_type(8)));
typedef float    f32x4 __attribute__((ext_vector_type(4)));

#define ROWF 256   // floats per token row (H*d = 4*64)
#define HDIM 64
#define KST 72     // LDS stride in halves
#define PST (16 * KST)

// intra-tile token offset: j = tt*64 + th*8 + tw  ->  2304*tt + 48*th + tw
__device__ __forceinline__ int intra_off(int j) {
    return 2304 * (j >> 6) + 48 * ((j >> 3) & 7) + (j & 7);
}

__global__ __launch_bounds__(256) void sta_kernel(
    const float* __restrict__ qg, const float* __restrict__ kg,
    const float* __restrict__ vg, float* __restrict__ out)
{
    __shared__ _Float16 Klds[64 * KST];   // [key][d]
    __shared__ _Float16 Vlds[64 * KST];   // transposed: [d][key]
    __shared__ _Float16 Plds[4 * PST];    // per-wave [q=16][key=64]

    const int tid  = threadIdx.x;
    const int wave = tid >> 6;
    const int lane = tid & 63;
    const int g    = lane >> 4;   // 0..3
    const int c    = lane & 15;   // 0..15

    const int bid  = blockIdx.x;
    const int tile = bid >> 3;          // 0..215
    const int head = (bid >> 1) & 3;    // 0..3
    const int rb   = bid & 1;           // query half

    const int nt = tile / 36;
    const int nh = (tile / 6) % 6;
    const int nw = tile % 6;
    const int tbase = 13824 * nt + 384 * nh + 8 * nw;

    // --- window-start base + packed per-window-tile kb deltas (16b each) ---
    int W, kb0; unsigned long long dpk;
    const int t0 = nt < 4 ? nt : 4;
    const int h0 = nh < 4 ? nh : 4;
    const int w0 = nw < 4 ? nw : 4;
    if (head == 0) {        // (2,1,1): tiles (t0, nh, nw), (t0+1, nh, nw)
        W = 2; kb0 = 13824 * t0 + 384 * nh + 8 * nw; dpk = (13824ULL << 16);
    } else if (head == 1) { // (1,2,2): (nt, h0+{0,1}, w0+{0,1})
        W = 4; kb0 = 13824 * nt + 384 * h0 + 8 * w0;
        dpk = (8ULL << 16) | (384ULL << 32) | (392ULL << 48);
    } else if (head == 2) { // (1,1,2): (nt, nh, w0+{0,1})
        W = 2; kb0 = 13824 * nt + 384 * nh + 8 * w0; dpk = (8ULL << 16);
    } else {                // (1,1,1)
        W = 1; kb0 = tbase; dpk = 0ULL;
    }
    const int NC = W * 6;

    // --- Q fragments: lane holds Q[q=mt*16+c][d-slice], scale folded (exp2 domain)
    const float qscale = 0.125f * 1.44269504f;
    half8 qf[3][2];
    #pragma unroll
    for (int mt = 0; mt < 3; ++mt) {
        const int j = rb * 192 + wave * 48 + mt * 16 + c;
        const float* qp = qg + (size_t)(tbase + intra_off(j)) * ROWF + head * HDIM;
        #pragma unroll
        for (int kc = 0; kc < 2; ++kc) {
            f32x4 a = *(const f32x4*)(qp + kc * 32 + g * 8);
            f32x4 b = *(const f32x4*)(qp + kc * 32 + g * 8 + 4);
            half8 f;
            #pragma unroll
            for (int e = 0; e < 4; ++e) {
                f[e]     = (_Float16)(a[e] * qscale);
                f[e + 4] = (_Float16)(b[e] * qscale);
            }
            qf[mt][kc] = f;
        }
    }

    f32x4 oacc[3][4];
    float m_r[3], l_r[3];
    #pragma unroll
    for (int mt = 0; mt < 3; ++mt) {
        #pragma unroll
        for (int dt = 0; dt < 4; ++dt) oacc[mt][dt] = (f32x4){0.f, 0.f, 0.f, 0.f};
        m_r[mt] = -1e30f; l_r[mt] = 0.f;
    }

    const int r4  = tid >> 4;   // key group of 4 (0..15)
    const int sc4 = tid & 15;   // d group of 4 (0..15)

    // per-thread token offsets within a 64-token chunk (compile-time unrolled)
    int toff0, toff1, toff2, toff3;
    {
        const int r0 = r4 * 4;
        toff0 = 48 * ((r0 + 0) >> 3) + ((r0 + 0) & 7);
        toff1 = 48 * ((r0 + 1) >> 3) + ((r0 + 1) & 7);
        toff2 = 48 * ((r0 + 2) >> 3) + ((r0 + 2) & 7);
        toff3 = 48 * ((r0 + 3) >> 3) + ((r0 + 3) & 7);
    }
    const size_t lin = (size_t)head * HDIM + sc4 * 4;

    // async staging registers (one chunk in flight)
    f32x4 kr0, kr1, kr2, kr3, vr0, vr1, vr2, vr3;

#define ISSUE(KB) do {                                                   \
        const size_t a0 = (size_t)((KB) + toff0) * ROWF + lin;           \
        const size_t a1 = (size_t)((KB) + toff1) * ROWF + lin;           \
        const size_t a2 = (size_t)((KB) + toff2) * ROWF + lin;           \
        const size_t a3 = (size_t)((KB) + toff3) * ROWF + lin;           \
        kr0 = *(const f32x4*)(kg + a0); vr0 = *(const f32x4*)(vg + a0);  \
        kr1 = *(const f32x4*)(kg + a1); vr1 = *(const f32x4*)(vg + a1);  \
        kr2 = *(const f32x4*)(kg + a2); vr2 = *(const f32x4*)(vg + a2);  \
        kr3 = *(const f32x4*)(kg + a3); vr3 = *(const f32x4*)(vg + a3);  \
    } while (0)

    // issue chunk 0 (wi=0, ktt=0)
    ISSUE(kb0);
    int ktt_n = 1, sh_n = 0;   // next chunk to issue: (sh_n selects window tile, ktt_n)

    for (int ci = 0; ci < NC; ++ci) {
        // --- commit staged regs: K row-major, V transposed (scalar RTN casts) ---
        {
            half4 kh;
            kh[0] = (_Float16)kr0[0]; kh[1] = (_Float16)kr0[1];
            kh[2] = (_Float16)kr0[2]; kh[3] = (_Float16)kr0[3];
            *(half4*)&Klds[(r4 * 4 + 0) * KST + sc4 * 4] = kh;
            kh[0] = (_Float16)kr1[0]; kh[1] = (_Float16)kr1[1];
            kh[2] = (_Float16)kr1[2]; kh[3] = (_Float16)kr1[3];
            *(half4*)&Klds[(r4 * 4 + 1) * KST + sc4 * 4] = kh;
            kh[0] = (_Float16)kr2[0]; kh[1] = (_Float16)kr2[1];
            kh[2] = (_Float16)kr2[2]; kh[3] = (_Float16)kr2[3];
            *(half4*)&Klds[(r4 * 4 + 2) * KST + sc4 * 4] = kh;
            kh[0] = (_Float16)kr3[0]; kh[1] = (_Float16)kr3[1];
            kh[2] = (_Float16)kr3[2]; kh[3] = (_Float16)kr3[3];
            *(half4*)&Klds[(r4 * 4 + 3) * KST + sc4 * 4] = kh;
            #pragma unroll
            for (int e = 0; e < 4; ++e) {
                half4 vh;
                vh[0] = (_Float16)vr0[e]; vh[1] = (_Float16)vr1[e];
                vh[2] = (_Float16)vr2[e]; vh[3] = (_Float16)vr3[e];
                *(half4*)&Vlds[(sc4 * 4 + e) * KST + r4 * 4] = vh;
            }
        }
        __syncthreads();   // staged chunk visible to all waves

        if (ci + 1 < NC) {   // overlap next chunk's HBM latency with compute below
            const int kbn = kb0 + (int)((dpk >> sh_n) & 0xFFFFULL) + 2304 * ktt_n;
            ISSUE(kbn);
            if (++ktt_n == 6) { ktt_n = 0; sh_n += 16; }
        }

        #pragma unroll
        for (int mt = 0; mt < 3; ++mt) {
            // --- S^T = K * Q^T : lane (g,c) holds S[q=c][key = jt*16 + g*4 + r] ---
            f32x4 sacc[4];
            #pragma unroll
            for (int jt = 0; jt < 4; ++jt) sacc[jt] = (f32x4){0.f, 0.f, 0.f, 0.f};
            #pragma unroll
            for (int kc = 0; kc < 2; ++kc) {
                const half8 qfr = qf[mt][kc];
                #pragma unroll
                for (int jt = 0; jt < 4; ++jt) {
                    const half8 kf = *(const half8*)&Klds[(jt * 16 + c) * KST + kc * 32 + g * 8];
                    sacc[jt] = __builtin_amdgcn_mfma_f32_16x16x32_f16(kf, qfr, sacc[jt], 0, 0, 0);
                }
            }
            // --- online softmax over 64 keys: 16 in-lane + 2 shuffles ---
            float mj[4];
            #pragma unroll
            for (int jt = 0; jt < 4; ++jt)
                mj[jt] = fmaxf(fmaxf(sacc[jt][0], sacc[jt][1]),
                               fmaxf(sacc[jt][2], sacc[jt][3]));
            float mm = fmaxf(fmaxf(mj[0], mj[1]), fmaxf(mj[2], mj[3]));
            mm = fmaxf(mm, __shfl_xor(mm, 16, 64));
            mm = fmaxf(mm, __shfl_xor(mm, 32, 64));
            const float mn = fmaxf(m_r[mt], mm);
            const float alpha = exp2f(m_r[mt] - mn);
            m_r[mt] = mn;

            float rsj[4];
            #pragma unroll
            for (int jt = 0; jt < 4; ++jt) {
                const float p0 = exp2f(sacc[jt][0] - mn);
                const float p1 = exp2f(sacc[jt][1] - mn);
                const float p2 = exp2f(sacc[jt][2] - mn);
                const float p3 = exp2f(sacc[jt][3] - mn);
                rsj[jt] = (p0 + p1) + (p2 + p3);
                half4 ph;
                ph[0] = (_Float16)p0; ph[1] = (_Float16)p1;
                ph[2] = (_Float16)p2; ph[3] = (_Float16)p3;
                *(half4*)&Plds[wave * PST + c * KST + jt * 16 + g * 4] = ph;
            }
            float rs = (rsj[0] + rsj[1]) + (rsj[2] + rsj[3]);
            rs += __shfl_xor(rs, 16, 64);
            rs += __shfl_xor(rs, 32, 64);
            l_r[mt] = l_r[mt] * alpha + rs;

            float ar[4];
            #pragma unroll
            for (int r = 0; r < 4; ++r) ar[r] = __shfl(alpha, g * 4 + r, 16);
            #pragma unroll
            for (int dt = 0; dt < 4; ++dt)
                #pragma unroll
                for (int r = 0; r < 4; ++r)
                    oacc[mt][dt][r] *= ar[r];

            // --- O += P V : A = P[q][k], B = V^T[d][k] ---
            #pragma unroll
            for (int kc = 0; kc < 2; ++kc) {
                const half8 pa = *(const half8*)&Plds[wave * PST + c * KST + kc * 32 + g * 8];
                #pragma unroll
                for (int dt = 0; dt < 4; ++dt) {
                    const half8 vb = *(const half8*)&Vlds[(dt * 16 + c) * KST + kc * 32 + g * 8];
                    oacc[mt][dt] = __builtin_amdgcn_mfma_f32_16x16x32_f16(pa, vb, oacc[mt][dt], 0, 0, 0);
                }
            }
        }
        __syncthreads();   // all reads of this chunk done before next commit overwrites
    }
#undef ISSUE

    // --- epilogue: normalize and scatter via untile ---
    #pragma unroll
    for (int mt = 0; mt < 3; ++mt) {
        float lq[4];
        #pragma unroll
        for (int r = 0; r < 4; ++r) lq[r] = __shfl(l_r[mt], g * 4 + r, 16);
        #pragma unroll
        for (int r = 0; r < 4; ++r) {
            const int j = rb * 192 + wave * 48 + mt * 16 + g * 4 + r;
            float* op = out + (size_t)(tbase + intra_off(j)) * ROWF + head * HDIM;
            const float linv = 1.0f / lq[r];
            #pragma unroll
            for (int dt = 0; dt < 4; ++dt)
                op[dt * 16 + c] = oacc[mt][dt][r] * linv;
        }
    }
}

extern "C" void kernel_launch(void* const* d_in, const int* in_sizes, int n_in,
                              void* d_out, int out_size, void* d_ws, size_t ws_size,
                              hipStream_t stream) {
    const float* q = (const float*)d_in[0];
    const float* k = (const float*)d_in[1];
    const float* v = (const float*)d_in[2];
    float* o = (float*)d_out;
    dim3 grid(216 * 4 * 2);   // tile * head * query-half
    dim3 block(256);
    hipLaunchKernelGGL(sta_kernel, grid, block, 0, stream, q, k, v, o);
}